// Round 12
// baseline (123.783 us; speedup 1.0000x reference)
//
#include <hip/hip_runtime.h>
#include <math.h>

// Problem sizes: B=16, Cin=1, CH=32, N0=128, F=512, G=4, N1=64, k1=9, N2=32, k2=7, NC=10
// Workspace offsets (float units)
#define OFF_D1   0          // 512
#define OFF_S1   512        // 8192  : s1[p][n]
#define OFF_T1   8704       // 576   : T1[p][k]
#define OFF_TWB  9280       // 7168 slots : bf16 tw2 packed [q][k][n]
#define OFF_T    16448      // 32768 : t[g][n][q]
#define OFF_A2   49216      // 16384 : ap[g][p][q] scratch
#define OFF_A2H  65600      // 8192 slots : bf16 hi of anorm2 [g][n][m]
#define OFF_A2L  73792      // 8192 slots : bf16 lo residual
#define OFF_PART 81984      // 512   : partial sums [b][c] (atomicAdd, zeroed by prep1)
#define OFF_AN1  82496      // 65536 : anorm1[g][n][m]
#define OFF_C1H  148032     // 147456 slots : bf16 hi C1[g][r][m]
#define OFF_C1L  295488     // 147456 slots : bf16 lo residual
#define OFF_XTH  442944     // 524288 slots : xT hi [b][g][f][m]
#define OFF_XTL  967232     // 524288 slots : xT lo
#define OFF_A    1491520    // 8388608 slots : v bf16 plain [b,o][p][f]
#define OFF_B    9880128    // 8388608 slots : h2T bf16 [b,o][f][n]
#define OFF_Z    18268736   // 4718592 : z fp32 [b][r=p*9+k][f]
#define OFF_CTR  22987328   // 1 : completion counter for k6 tail

typedef short bf16x8 __attribute__((ext_vector_type(8)));
typedef short short4v __attribute__((ext_vector_type(4)));
typedef float f32x4 __attribute__((ext_vector_type(4)));

static __device__ __forceinline__ unsigned short f2bf(float x) {
  union { float f; unsigned u; } v; v.f = x;
  unsigned r = v.u + 0x7FFF + ((v.u >> 16) & 1);   // RNE
  return (unsigned short)(r >> 16);
}
static __device__ __forceinline__ float bf2f(unsigned short h) {
  union { unsigned u; float f; } v; v.u = ((unsigned)h) << 16;
  return v.f;
}

// ---------------- PREP1 = p1 (d1,s1,T1,twB) + pxt (x transpose/split) ----------------
__global__ __launch_bounds__(256) void prep1_kernel(const float* __restrict__ adj,
    const float* __restrict__ tw1, const float* __restrict__ rp1,
    const float* __restrict__ tw2, const float* __restrict__ x,
    float* __restrict__ ws) {
  int t = threadIdx.x;
  if (blockIdx.x == 0) {                 // reset k6 tail ctr + zero PART accumulators
    if (t == 0) ((unsigned*)(ws + OFF_CTR))[0] = 0u;
    ws[OFF_PART + t] = 0.0f;
    ws[OFF_PART + 256 + t] = 0.0f;
  }
  if (blockIdx.x < 93) {
    int idx = blockIdx.x * 256 + t;
    if (idx < 512) {
      int g = idx >> 7, n = idx & 127;
      const float* row = adj + (g * 128 + n) * 128;
      float s = 1.0f;
      for (int m = 0; m < 128; ++m) s += row[m];
      ws[OFF_D1 + idx] = 1.0f / sqrtf(fmaxf(s, 1.0f));
    } else if (idx < 8704) {
      int r = idx - 512; int p = r >> 7, n = r & 127;
      const float* tp = tw1 + (p * 128 + n) * 9;
      float s = 0.f;
#pragma unroll
      for (int k = 0; k < 9; ++k) s += tp[k] * rp1[k];
      ws[OFF_S1 + r] = s;
    } else if (idx < 9280) {
      int r = idx - 8704; int p = r / 9, k = r - p * 9;
      float s = 0.f;
      for (int n = 0; n < 128; ++n) s += tw1[(p * 128 + n) * 9 + k];
      ws[OFF_T1 + r] = s;
    } else if (idx < 23616) {            // twB bf16 [q][k][n]
      int r = idx - 9280;
      int q = r / 448, rem = r - q * 448;
      int k = rem >> 6, n = rem & 63;
      ((unsigned short*)(ws + OFF_TWB))[r] = f2bf(tw2[(q * 64 + n) * 7 + k]);
    }
  } else {                               // pxt: transpose x via padded LDS
    __shared__ float XP[128 * 129];
    int i = blockIdx.x - 93;
    int b = i >> 2, g = i & 3;
#pragma unroll
    for (int ii = 0; ii < 16; ++ii) {
      int e = ii * 256 + t;
      int f4 = e & 31, m = e >> 5;
      float4 v = *(const float4*)&x[(size_t)(b * 128 + m) * 512 + g * 128 + f4 * 4];
      XP[m * 129 + f4 * 4 + 0] = v.x;
      XP[m * 129 + f4 * 4 + 1] = v.y;
      XP[m * 129 + f4 * 4 + 2] = v.z;
      XP[m * 129 + f4 * 4 + 3] = v.w;
    }
    __syncthreads();
    unsigned short* XH = (unsigned short*)(ws + OFF_XTH) + (size_t)(b * 4 + g) * 16384;
    unsigned short* XL = (unsigned short*)(ws + OFF_XTL) + (size_t)(b * 4 + g) * 16384;
#pragma unroll
    for (int ii = 0; ii < 8; ++ii) {
      int e = ii * 256 + t;
      int f = e >> 4, m8 = e & 15;
      unsigned short hs[8], ls[8];
#pragma unroll
      for (int j = 0; j < 8; ++j) {
        float v = XP[(m8 * 8 + j) * 129 + f];
        unsigned short h = f2bf(v);
        hs[j] = h;
        ls[j] = f2bf(v - bf2f(h));
      }
      *(uint4*)&XH[f * 128 + m8 * 8] = *(uint4*)hs;
      *(uint4*)&XL[f * 128 + m8 * 8] = *(uint4*)ls;
    }
  }
}

// ---------------- PREP2 = p1b (anorm1) + p2 (t) ----------------
__global__ __launch_bounds__(256) void prep2_kernel(const float* __restrict__ adj,
                                                    float* __restrict__ ws) {
  int t = threadIdx.x;
  if (blockIdx.x < 256) {
    int idx = blockIdx.x * 256 + t;      // 65536
    int g = idx >> 14, n = (idx >> 7) & 127, m = idx & 127;
    float v = adj[idx] + (n == m ? 1.0f : 0.0f);
    ws[OFF_AN1 + idx] = ws[OFF_D1 + g * 128 + n] * ws[OFF_D1 + g * 128 + m] * v;
  } else {
    int idx = (blockIdx.x - 256) * 256 + t;   // 32768
    int g = idx >> 13, n = (idx >> 6) & 127, q = idx & 63;
    const float* row = adj + (g * 128 + n) * 128;
    const float* s1 = ws + OFF_S1 + q * 128;
    float s = 0.f;
    for (int m = 0; m < 128; ++m) s += row[m] * s1[m];
    ws[OFF_T + idx] = s;
  }
}

// ---------------- PREP3 = p3a (ap) + pC1 (C1 split-bf16) ----------------
__global__ __launch_bounds__(256) void prep3_kernel(const float* __restrict__ tw1,
                                                    float* __restrict__ ws) {
  int t = threadIdx.x;
  if (blockIdx.x < 64) {                 // p3a
    int g = blockIdx.x & 3, pt = blockIdx.x >> 2;
    int pp = t >> 6, q = t & 63;
    int p = pt * 4 + pp;
    const float* s1 = ws + OFF_S1 + p * 128;
    const float* tg = ws + OFF_T + g * 8192;
    float s = 0.f;
#pragma unroll 4
    for (int n = 0; n < 128; ++n) s += s1[n] * tg[n * 64 + q];
    ws[OFF_A2 + g * 4096 + p * 64 + q] = s;
  } else {                               // pC1
    int i = blockIdx.x - 64;
    int g = i / 288, rb = i - g * 288;
    int r = rb * 2 + (t >> 7), m = t & 127;
    int p = r / 9, k = r - p * 9;
    const float* an = ws + OFF_AN1 + g * 16384;
    float s = 0.f;
#pragma unroll 4
    for (int n = 0; n < 128; ++n)
      s += tw1[(p * 128 + n) * 9 + k] * an[n * 128 + m];
    unsigned short hi = f2bf(s);
    float lo = s - bf2f(hi);
    ((unsigned short*)(ws + OFF_C1H))[((size_t)g * 576 + r) * 128 + m] = hi;
    ((unsigned short*)(ws + OFF_C1L))[((size_t)g * 576 + r) * 128 + m] = f2bf(lo);
  }
}

// ---- kz: z = C1 * x via 3-term split MFMA ; rt==9 slice runs prep4 (pooled-adj norm) ----
__global__ __launch_bounds__(512) void kz_mfma(float* __restrict__ ws) {
  __shared__ __align__(16) unsigned char smH[32768];
  __shared__ __align__(16) unsigned char smL[32768];
  int b = blockIdx.x, rt = blockIdx.y, g = blockIdx.z, t = threadIdx.x;
  if (rt == 9) {                         // prep4: normalize pooled adjacency
    if (g != 0 || b >= 4) return;
    float* ap = (float*)smH;             // 16 KB
    float* d2 = (float*)smL;
    for (int i = t; i < 4096; i += 512) ap[i] = ws[OFF_A2 + b * 4096 + i];
    __syncthreads();
    if (t < 64) {
      float s = 1.0f;
      for (int q = 0; q < 64; ++q) s += ap[t * 64 + q];
      d2[t] = 1.0f / sqrtf(fmaxf(s, 1.0f));
    }
    __syncthreads();
    for (int i = t; i < 4096; i += 512) {
      int p = i >> 6, q = i & 63;
      float fullv = d2[p] * d2[q] * (ap[i] + (p == q ? 1.0f : 0.0f));
      unsigned short hi = f2bf(fullv);
      float lo = fullv - bf2f(hi);
      ((unsigned short*)(ws + OFF_A2H))[b * 4096 + i] = hi;
      ((unsigned short*)(ws + OFF_A2L))[b * 4096 + i] = f2bf(lo);
    }
    return;
  }
  const uint4* XH = (const uint4*)((const unsigned short*)(ws + OFF_XTH) +
                                   (size_t)(b * 4 + g) * 16384);
  const uint4* XL = (const uint4*)((const unsigned short*)(ws + OFF_XTL) +
                                   (size_t)(b * 4 + g) * 16384);
#pragma unroll
  for (int i = 0; i < 4; ++i) {
    int e = i * 512 + t;
    int f = e >> 4, s = e & 15;
    int slot = s ^ (f & 7);
    *(uint4*)(smH + f * 256 + slot * 16) = XH[e];
    *(uint4*)(smL + f * 256 + slot * 16) = XL[e];
  }
  int w = t >> 6, l = t & 63, ll = l & 15, lhi = l >> 4;
  int wm = w & 3, wn = w >> 2;
  const unsigned short* c1h = (const unsigned short*)(ws + OFF_C1H) +
                              ((size_t)g * 576 + rt * 64 + wm * 16 + ll) * 128;
  const unsigned short* c1l = (const unsigned short*)(ws + OFF_C1L) +
                              ((size_t)g * 576 + rt * 64 + wm * 16 + ll) * 128;
  bf16x8 Ah[4], Al[4];
#pragma unroll
  for (int ks = 0; ks < 4; ++ks) {
    Ah[ks] = *(const bf16x8*)(c1h + ks * 32 + lhi * 8);
    Al[ks] = *(const bf16x8*)(c1l + ks * 32 + lhi * 8);
  }
  __syncthreads();
  float* zb = ws + OFF_Z + ((size_t)b * 576 + rt * 64 + wm * 16) * 512 + g * 128 + wn * 64;
#pragma unroll
  for (int Nt = 0; Nt < 4; ++Nt) {
    int f = wn * 64 + Nt * 16 + ll;
    bf16x8 Bh[4], Bl[4];
#pragma unroll
    for (int ks = 0; ks < 4; ++ks) {
      int slot = (ks * 4 + lhi) ^ (f & 7);
      Bh[ks] = *(const bf16x8*)(smH + f * 256 + slot * 16);
      Bl[ks] = *(const bf16x8*)(smL + f * 256 + slot * 16);
    }
    f32x4 acc = {0.f, 0.f, 0.f, 0.f};
#pragma unroll
    for (int ks = 0; ks < 4; ++ks) {
      acc = __builtin_amdgcn_mfma_f32_16x16x32_bf16(Ah[ks], Bh[ks], acc, 0, 0, 0);
      acc = __builtin_amdgcn_mfma_f32_16x16x32_bf16(Ah[ks], Bl[ks], acc, 0, 0, 0);
      acc = __builtin_amdgcn_mfma_f32_16x16x32_bf16(Al[ks], Bh[ks], acc, 0, 0, 0);
    }
#pragma unroll
    for (int i = 0; i < 4; ++i)
      zb[(lhi * 4 + i) * 512 + Nt * 16 + ll] = acc[i];
  }
}

// -------- fused: x2[c,f] = relu(sum_k W1*z + b1*Tsum + tb1) ; v = W2*x2 via MFMA
__global__ __launch_bounds__(256) void k45m(const float* __restrict__ W1,
    const float* __restrict__ b1, const float* __restrict__ tb1,
    const float* __restrict__ W2, float* __restrict__ ws) {
  __shared__ float W1s[128];
  __shared__ float b1s[32];
  __shared__ float T1s[9];
  __shared__ __align__(16) unsigned short X2s[256 * 40];
  int b = blockIdx.x, p = blockIdx.y, t = threadIdx.x;
  if (t < 128) W1s[t] = W1[t];
  else if (t < 160) b1s[t - 128] = b1[t - 128];
  else if (t < 169) T1s[t - 160] = ws[OFF_T1 + p * 9 + (t - 160)];
  float tb = tb1[p];
  __syncthreads();
  const float* z = ws + OFF_Z + (size_t)b * 294912 + (size_t)p * 4608;
  unsigned short* vb = (unsigned short*)(ws + OFF_A);
  int w = t >> 6, l = t & 63, ll = l & 15, lhi = l >> 4;
  for (int pass = 0; pass < 2; ++pass) {
    int f = pass * 256 + t;
    float zv[9]; int gk[9];
    float tsum = 0.f;
#pragma unroll
    for (int k = 0; k < 9; ++k) {
      int fp = f + k - 4;
      bool val = (fp >= 0 && fp < 512);
      zv[k] = val ? z[k * 512 + fp] : 0.0f;
      gk[k] = val ? (fp >> 7) : 0;
      tsum += val ? T1s[k] : 0.0f;
    }
    float acc[32];
#pragma unroll
    for (int c = 0; c < 32; ++c) acc[c] = b1s[c] * tsum + tb;
#pragma unroll
    for (int k = 0; k < 9; ++k) {
      const float4* Wc = (const float4*)&W1s[gk[k] * 32];
      float zk = zv[k];
#pragma unroll
      for (int c4 = 0; c4 < 8; ++c4) {
        float4 wv = Wc[c4];
        acc[c4 * 4 + 0] += wv.x * zk;
        acc[c4 * 4 + 1] += wv.y * zk;
        acc[c4 * 4 + 2] += wv.z * zk;
        acc[c4 * 4 + 3] += wv.w * zk;
      }
    }
    __syncthreads();
#pragma unroll
    for (int grp = 0; grp < 4; ++grp) {
      unsigned short hs[8];
#pragma unroll
      for (int j = 0; j < 8; ++j) hs[j] = f2bf(fmaxf(acc[grp * 8 + j], 0.0f));
      *(uint4*)&X2s[t * 40 + grp * 8] = *(uint4*)hs;
    }
    __syncthreads();
    int g = pass * 2 + (w >> 1);
    const float* W2g = W2 + g * 1024;
    bf16x8 Ah[2], Al[2];
#pragma unroll
    for (int Mt = 0; Mt < 2; ++Mt) {
      const float* wp = W2g + (Mt * 16 + ll) * 32 + lhi * 8;
      float wv[8];
      *(float4*)&wv[0] = *(const float4*)wp;
      *(float4*)&wv[4] = *(const float4*)(wp + 4);
      unsigned short hh[8], lw[8];
#pragma unroll
      for (int j = 0; j < 8; ++j) {
        unsigned short h = f2bf(wv[j]);
        hh[j] = h;
        lw[j] = f2bf(wv[j] - bf2f(h));
      }
      Ah[Mt] = *(bf16x8*)hh;
      Al[Mt] = *(bf16x8*)lw;
    }
#pragma unroll
    for (int Nt = 0; Nt < 4; ++Nt) {
      int frow = w * 64 + Nt * 16 + ll;
      bf16x8 Bf = *(const bf16x8*)&X2s[frow * 40 + lhi * 8];
      f32x4 accv[2] = {{0.f, 0.f, 0.f, 0.f}, {0.f, 0.f, 0.f, 0.f}};
#pragma unroll
      for (int Mt = 0; Mt < 2; ++Mt) {
        accv[Mt] = __builtin_amdgcn_mfma_f32_16x16x32_bf16(Ah[Mt], Bf, accv[Mt], 0, 0, 0);
        accv[Mt] = __builtin_amdgcn_mfma_f32_16x16x32_bf16(Al[Mt], Bf, accv[Mt], 0, 0, 0);
      }
      int fglob = pass * 256 + frow;
#pragma unroll
      for (int Mt = 0; Mt < 2; ++Mt)
#pragma unroll
        for (int i = 0; i < 4; ++i) {
          int o = Mt * 16 + lhi * 4 + i;
          vb[((size_t)(b * 32 + o) * 64 + p) * 512 + fglob] = f2bf(accv[Mt][i]);
        }
    }
    __syncthreads();
  }
}

// ---- h2T[b,o,f,n] (bf16) = sum_m anorm2[g(f),n,m]*v[b,o,m,f] + b2[o] via MFMA ----
__global__ __launch_bounds__(256) void k5b_h2(const float* __restrict__ b2,
                                              float* __restrict__ ws) {
  __shared__ __align__(16) unsigned short vT[128 * 64];   // rows fl (128B), swizzled
  int b = blockIdx.x, o = blockIdx.y, g = blockIdx.z, t = threadIdx.x;
  const unsigned short* vbp = (const unsigned short*)(ws + OFF_A) +
                              (size_t)(b * 32 + o) * 32768;
  const uint4* vb4 = (const uint4*)vbp;
  unsigned char* vTw = (unsigned char*)vT;
  for (int i = t; i < 1024; i += 256) {
    int p = i >> 4, u = i & 15;
    uint4 val = vb4[p * 64 + g * 16 + u];
    const unsigned short* hv = (const unsigned short*)&val;
#pragma unroll
    for (int e = 0; e < 8; ++e) {
      int fl = u * 8 + e;
      int addr = fl * 128 + ((p * 2) ^ ((((fl & 7) ^ (fl >> 3)) & 7) << 4));
      *(unsigned short*)(vTw + addr) = hv[e];
    }
  }
  int w = t >> 6, l = t & 63, ll = l & 15, lhi = l >> 4;
  const unsigned short* a2h = (const unsigned short*)(ws + OFF_A2H) + g * 4096;
  const unsigned short* a2l = (const unsigned short*)(ws + OFF_A2L) + g * 4096;
  bf16x8 Ah[4][2], Al[4][2];
#pragma unroll
  for (int Mt = 0; Mt < 4; ++Mt)
#pragma unroll
    for (int ks = 0; ks < 2; ++ks) {
      int idx = (Mt * 16 + ll) * 64 + ks * 32 + lhi * 8;
      Ah[Mt][ks] = *(const bf16x8*)(a2h + idx);
      Al[Mt][ks] = *(const bf16x8*)(a2l + idx);
    }
  float bias = b2[o];
  __syncthreads();
  unsigned short* h2T = (unsigned short*)(ws + OFF_B) + (size_t)(b * 32 + o) * 32768;
  const unsigned char* vTr = (const unsigned char*)vT;
#pragma unroll
  for (int fi = 0; fi < 2; ++fi) {
    int fgl = w * 2 + fi;
    int fl = fgl * 16 + ll;
    int swz = (((fl & 7) ^ (fl >> 3)) & 7) << 4;
    bf16x8 Bf[2];
#pragma unroll
    for (int ks = 0; ks < 2; ++ks)
      Bf[ks] = *(const bf16x8*)(vTr + fl * 128 + ((ks * 64 + lhi * 16) ^ swz));
#pragma unroll
    for (int Mt = 0; Mt < 4; ++Mt) {
      f32x4 acc = {0.f, 0.f, 0.f, 0.f};
      acc = __builtin_amdgcn_mfma_f32_16x16x32_bf16(Ah[Mt][0], Bf[0], acc, 0, 0, 0);
      acc = __builtin_amdgcn_mfma_f32_16x16x32_bf16(Al[Mt][0], Bf[0], acc, 0, 0, 0);
      acc = __builtin_amdgcn_mfma_f32_16x16x32_bf16(Ah[Mt][1], Bf[1], acc, 0, 0, 0);
      acc = __builtin_amdgcn_mfma_f32_16x16x32_bf16(Al[Mt][1], Bf[1], acc, 0, 0, 0);
      int f = g * 128 + fgl * 16 + ll;
      int n0 = Mt * 16 + lhi * 4;
      unsigned short hs[4];
#pragma unroll
      for (int i2 = 0; i2 < 4; ++i2) hs[i2] = f2bf(acc[i2] + bias);
      *(short4v*)(h2T + f * 64 + n0) = *(short4v*)hs;
    }
  }
}

// ------- conv2: fh-split (2 blocks per (b,c)), in-loop A-frags, 62.8 KB LDS -------
// rows r=0..261 of h2s hold f = fh*256 + r - 3 (zero-padded at global edges)
#define L_TWB 33536    // 262*128
#define L_RED 62720    // 8 floats
#define L_FLAG 62752   // 1 uint
__global__ __launch_bounds__(512) void k6_conv2(const float* __restrict__ tb2,
    const float* __restrict__ Wout, const float* __restrict__ bout,
    float* __restrict__ ws, float* __restrict__ out) {
  __shared__ __align__(16) unsigned char sm[62756];
  int b = blockIdx.x, c = blockIdx.y, fh = blockIdx.z, t = threadIdx.x;
  const uint4* h2T4 = (const uint4*)((const unsigned short*)(ws + OFF_B) +
                                     (size_t)(b * 32 + c) * 32768);
  for (int ci = t; ci < 2096; ci += 512) {   // 262 rows x 8 slots
    int r = ci >> 3, slot = ci & 7;
    int f = fh * 256 + r - 3;
    uint4 val = make_uint4(0u, 0u, 0u, 0u);
    if (f >= 0 && f < 512) val = h2T4[f * 8 + slot];
    *(uint4*)(sm + r * 128 + ((slot ^ (r & 7)) << 4)) = val;
  }
  const uint4* twg = (const uint4*)(ws + OFF_TWB);
  for (int ci = t; ci < 1792; ci += 512) {
    int q = ci / 56, rem = ci - q * 56;
    *(uint4*)(sm + L_TWB + q * 912 + rem * 16) = twg[ci];
  }
  __syncthreads();
  int w = t >> 6, l = t & 63;
  int ll = l & 15, lhi = l >> 4;
  f32x4 acc[2][2];
#pragma unroll
  for (int Mt = 0; Mt < 2; ++Mt)
#pragma unroll
    for (int Nt = 0; Nt < 2; ++Nt) acc[Mt][Nt] = {0.f, 0.f, 0.f, 0.f};
  int rbase = w * 32 + ll;
#pragma unroll
  for (int ks = 0; ks < 14; ++ks) {
    bf16x8 A0 = *(const bf16x8*)(sm + L_TWB + (0 * 16 + ll) * 912 + (ks >> 1) * 128 +
                                 (ks & 1) * 64 + lhi * 16);
    bf16x8 A1 = *(const bf16x8*)(sm + L_TWB + (1 * 16 + ll) * 912 + (ks >> 1) * 128 +
                                 (ks & 1) * 64 + lhi * 16);
    int rb = rbase + (ks >> 1);
    int x = (((ks & 1) * 4 + lhi) ^ (rb & 7)) << 4;
#pragma unroll
    for (int Nt = 0; Nt < 2; ++Nt) {
      bf16x8 Bf = *(const bf16x8*)(sm + (rb + Nt * 16) * 128 + x);
      acc[0][Nt] = __builtin_amdgcn_mfma_f32_16x16x32_bf16(A0, Bf, acc[0][Nt], 0, 0, 0);
      acc[1][Nt] = __builtin_amdgcn_mfma_f32_16x16x32_bf16(A1, Bf, acc[1][Nt], 0, 0, 0);
    }
  }
  float tbv[8];
#pragma unroll
  for (int Mt = 0; Mt < 2; ++Mt)
#pragma unroll
    for (int i = 0; i < 4; ++i) tbv[Mt * 4 + i] = tb2[Mt * 16 + lhi * 4 + i];
  float s = 0.f;
#pragma unroll
  for (int Mt = 0; Mt < 2; ++Mt)
#pragma unroll
    for (int Nt = 0; Nt < 2; ++Nt)
#pragma unroll
      for (int i = 0; i < 4; ++i)
        s += fmaxf(acc[Mt][Nt][i] + tbv[Mt * 4 + i], 0.0f);
#pragma unroll
  for (int off = 32; off > 0; off >>= 1) s += __shfl_down(s, off, 64);
  float* red = (float*)(sm + L_RED);
  if (l == 0) red[w] = s;
  __syncthreads();
  if (t == 0) {
    float tot = 0.f;
    for (int i = 0; i < 8; ++i) tot += red[i];
    atomicAdd(&ws[OFF_PART + b * 32 + c], tot);    // 2 commutative adds (fh=0,1)
    __threadfence();
    unsigned old = atomicAdd((unsigned*)(ws + OFF_CTR), 1u);
    *(volatile unsigned*)(sm + L_FLAG) = (old == 1023u) ? 1u : 0u;
  }
  __syncthreads();
  if (*(volatile unsigned*)(sm + L_FLAG)) {        // last block: final mean + linear
    __threadfence();
    float* feat = (float*)sm;                       // reuse h2s area
    if (t < 512) feat[t] = ws[OFF_PART + t] * (1.0f / 16384.0f);
    __syncthreads();
    if (t < 160) {
      int bb = t / 10, j = t - bb * 10;
      float accf = bout[j];
      for (int c2 = 0; c2 < 32; ++c2) accf += feat[bb * 32 + c2] * Wout[j * 32 + c2];
      out[t] = accf;
    }
  }
}

extern "C" void kernel_launch(void* const* d_in, const int* in_sizes, int n_in,
                              void* d_out, int out_size, void* d_ws, size_t ws_size,
                              hipStream_t stream) {
  const float* x    = (const float*)d_in[0];
  const float* adj  = (const float*)d_in[1];
  const float* W1   = (const float*)d_in[2];
  const float* b1   = (const float*)d_in[3];
  const float* tw1  = (const float*)d_in[4];
  const float* tb1  = (const float*)d_in[5];
  const float* rp1  = (const float*)d_in[6];
  const float* W2   = (const float*)d_in[7];
  const float* b2   = (const float*)d_in[8];
  const float* tw2  = (const float*)d_in[9];
  const float* tb2  = (const float*)d_in[10];
  // d_in[11] = rp2 : unused (second pooled adjacency is dead in the reference)
  const float* Wout = (const float*)d_in[12];
  const float* bout = (const float*)d_in[13];
  float* out = (float*)d_out;
  float* ws = (float*)d_ws;

  prep1_kernel<<<157, 256, 0, stream>>>(adj, tw1, rp1, tw2, x, ws);
  prep2_kernel<<<384, 256, 0, stream>>>(adj, ws);
  prep3_kernel<<<1216, 256, 0, stream>>>(tw1, ws);
  kz_mfma     <<<dim3(16, 10, 4), 512, 0, stream>>>(ws);
  k45m        <<<dim3(16, 64), 256, 0, stream>>>(W1, b1, tb1, W2, ws);
  k5b_h2      <<<dim3(16, 32, 4), 256, 0, stream>>>(b2, ws);
  k6_conv2    <<<dim3(16, 32, 2), 512, 0, stream>>>(tb2, Wout, bout, ws, out);
}

// Round 13
// 116.244 us; speedup vs baseline: 1.0649x; 1.0649x over previous
//
#include <hip/hip_runtime.h>
#include <math.h>

// Problem sizes: B=16, Cin=1, CH=32, N0=128, F=512, G=4, N1=64, k1=9, N2=32, k2=7, NC=10
// Workspace offsets (float units)
#define OFF_D1   0          // 512
#define OFF_S1   512        // 8192  : s1[p][n]
#define OFF_T1   8704       // 576   : T1[p][k]
#define OFF_TWB  9280       // 7168 slots : bf16 tw2 packed [q][k][n]
#define OFF_T    16448      // 32768 : t[g][n][q]
#define OFF_A2   49216      // 16384 : ap[g][p][q] scratch
#define OFF_A2H  65600      // 8192 slots : bf16 hi of anorm2 [g][n][m]
#define OFF_A2L  73792      // 8192 slots : bf16 lo residual
#define OFF_PART 81984      // 512   : partial sums [b][c]
#define OFF_AN1  82496      // 65536 : anorm1[g][n][m]
#define OFF_C1H  148032     // 147456 slots : bf16 hi C1[g][r][m]
#define OFF_C1L  295488     // 147456 slots : bf16 lo residual
#define OFF_XTH  442944     // 524288 slots : xT hi [b][g][f][m]
#define OFF_XTL  967232     // 524288 slots : xT lo
#define OFF_A    1491520    // 8388608 slots : v bf16 plain [b,o][p][f]
#define OFF_B    9880128    // 8388608 slots : h2T bf16 [b,o][f][n]
#define OFF_Z    18268736   // 4718592 : z fp32 [b][r=p*9+k][f]
#define OFF_CTR  22987328   // 1 : completion counter for k6 tail

typedef short bf16x8 __attribute__((ext_vector_type(8)));
typedef short short4v __attribute__((ext_vector_type(4)));
typedef float f32x4 __attribute__((ext_vector_type(4)));

static __device__ __forceinline__ unsigned short f2bf(float x) {
  union { float f; unsigned u; } v; v.f = x;
  unsigned r = v.u + 0x7FFF + ((v.u >> 16) & 1);   // RNE
  return (unsigned short)(r >> 16);
}
static __device__ __forceinline__ float bf2f(unsigned short h) {
  union { unsigned u; float f; } v; v.u = ((unsigned)h) << 16;
  return v.f;
}

// ---------------- PREP1 = p1 (d1,s1,T1,twB) + pxt (x transpose/split) ----------------
__global__ __launch_bounds__(256) void prep1_kernel(const float* __restrict__ adj,
    const float* __restrict__ tw1, const float* __restrict__ rp1,
    const float* __restrict__ tw2, const float* __restrict__ x,
    float* __restrict__ ws) {
  int t = threadIdx.x;
  if (blockIdx.x == 0 && t == 0) ((unsigned*)(ws + OFF_CTR))[0] = 0u;  // reset k6 tail ctr
  if (blockIdx.x < 93) {
    int idx = blockIdx.x * 256 + t;
    if (idx < 512) {
      int g = idx >> 7, n = idx & 127;
      const float* row = adj + (g * 128 + n) * 128;
      float s = 1.0f;
      for (int m = 0; m < 128; ++m) s += row[m];
      ws[OFF_D1 + idx] = 1.0f / sqrtf(fmaxf(s, 1.0f));
    } else if (idx < 8704) {
      int r = idx - 512; int p = r >> 7, n = r & 127;
      const float* tp = tw1 + (p * 128 + n) * 9;
      float s = 0.f;
#pragma unroll
      for (int k = 0; k < 9; ++k) s += tp[k] * rp1[k];
      ws[OFF_S1 + r] = s;
    } else if (idx < 9280) {
      int r = idx - 8704; int p = r / 9, k = r - p * 9;
      float s = 0.f;
      for (int n = 0; n < 128; ++n) s += tw1[(p * 128 + n) * 9 + k];
      ws[OFF_T1 + r] = s;
    } else if (idx < 23616) {            // twB bf16 [q][k][n]
      int r = idx - 9280;
      int q = r / 448, rem = r - q * 448;
      int k = rem >> 6, n = rem & 63;
      ((unsigned short*)(ws + OFF_TWB))[r] = f2bf(tw2[(q * 64 + n) * 7 + k]);
    }
  } else {                               // pxt: transpose x via padded LDS
    __shared__ float XP[128 * 129];
    int i = blockIdx.x - 93;
    int b = i >> 2, g = i & 3;
#pragma unroll
    for (int ii = 0; ii < 16; ++ii) {
      int e = ii * 256 + t;
      int f4 = e & 31, m = e >> 5;
      float4 v = *(const float4*)&x[(size_t)(b * 128 + m) * 512 + g * 128 + f4 * 4];
      XP[m * 129 + f4 * 4 + 0] = v.x;
      XP[m * 129 + f4 * 4 + 1] = v.y;
      XP[m * 129 + f4 * 4 + 2] = v.z;
      XP[m * 129 + f4 * 4 + 3] = v.w;
    }
    __syncthreads();
    unsigned short* XH = (unsigned short*)(ws + OFF_XTH) + (size_t)(b * 4 + g) * 16384;
    unsigned short* XL = (unsigned short*)(ws + OFF_XTL) + (size_t)(b * 4 + g) * 16384;
#pragma unroll
    for (int ii = 0; ii < 8; ++ii) {
      int e = ii * 256 + t;
      int f = e >> 4, m8 = e & 15;
      unsigned short hs[8], ls[8];
#pragma unroll
      for (int j = 0; j < 8; ++j) {
        float v = XP[(m8 * 8 + j) * 129 + f];
        unsigned short h = f2bf(v);
        hs[j] = h;
        ls[j] = f2bf(v - bf2f(h));
      }
      *(uint4*)&XH[f * 128 + m8 * 8] = *(uint4*)hs;
      *(uint4*)&XL[f * 128 + m8 * 8] = *(uint4*)ls;
    }
  }
}

// ---------------- PREP2 = p1b (anorm1) + p2 (t) ----------------
__global__ __launch_bounds__(256) void prep2_kernel(const float* __restrict__ adj,
                                                    float* __restrict__ ws) {
  int t = threadIdx.x;
  if (blockIdx.x < 256) {
    int idx = blockIdx.x * 256 + t;      // 65536
    int g = idx >> 14, n = (idx >> 7) & 127, m = idx & 127;
    float v = adj[idx] + (n == m ? 1.0f : 0.0f);
    ws[OFF_AN1 + idx] = ws[OFF_D1 + g * 128 + n] * ws[OFF_D1 + g * 128 + m] * v;
  } else {
    int idx = (blockIdx.x - 256) * 256 + t;   // 32768
    int g = idx >> 13, n = (idx >> 6) & 127, q = idx & 63;
    const float* row = adj + (g * 128 + n) * 128;
    const float* s1 = ws + OFF_S1 + q * 128;
    float s = 0.f;
    for (int m = 0; m < 128; ++m) s += row[m] * s1[m];
    ws[OFF_T + idx] = s;
  }
}

// ---------------- PREP3 = p3a (ap) + pC1 (C1 split-bf16) ----------------
__global__ __launch_bounds__(256) void prep3_kernel(const float* __restrict__ tw1,
                                                    float* __restrict__ ws) {
  int t = threadIdx.x;
  if (blockIdx.x < 64) {                 // p3a
    int g = blockIdx.x & 3, pt = blockIdx.x >> 2;
    int pp = t >> 6, q = t & 63;
    int p = pt * 4 + pp;
    const float* s1 = ws + OFF_S1 + p * 128;
    const float* tg = ws + OFF_T + g * 8192;
    float s = 0.f;
#pragma unroll 4
    for (int n = 0; n < 128; ++n) s += s1[n] * tg[n * 64 + q];
    ws[OFF_A2 + g * 4096 + p * 64 + q] = s;
  } else {                               // pC1
    int i = blockIdx.x - 64;
    int g = i / 288, rb = i - g * 288;
    int r = rb * 2 + (t >> 7), m = t & 127;
    int p = r / 9, k = r - p * 9;
    const float* an = ws + OFF_AN1 + g * 16384;
    float s = 0.f;
#pragma unroll 4
    for (int n = 0; n < 128; ++n)
      s += tw1[(p * 128 + n) * 9 + k] * an[n * 128 + m];
    unsigned short hi = f2bf(s);
    float lo = s - bf2f(hi);
    ((unsigned short*)(ws + OFF_C1H))[((size_t)g * 576 + r) * 128 + m] = hi;
    ((unsigned short*)(ws + OFF_C1L))[((size_t)g * 576 + r) * 128 + m] = f2bf(lo);
  }
}

// ---- kz: z = C1 * x via 3-term split MFMA ; rt==9 slice runs prep4 (pooled-adj norm) ----
__global__ __launch_bounds__(512) void kz_mfma(float* __restrict__ ws) {
  __shared__ __align__(16) unsigned char smH[32768];
  __shared__ __align__(16) unsigned char smL[32768];
  int b = blockIdx.x, rt = blockIdx.y, g = blockIdx.z, t = threadIdx.x;
  if (rt == 9) {                         // prep4: normalize pooled adjacency
    if (g != 0 || b >= 4) return;
    float* ap = (float*)smH;             // 16 KB
    float* d2 = (float*)smL;
    for (int i = t; i < 4096; i += 512) ap[i] = ws[OFF_A2 + b * 4096 + i];
    __syncthreads();
    if (t < 64) {
      float s = 1.0f;
      for (int q = 0; q < 64; ++q) s += ap[t * 64 + q];
      d2[t] = 1.0f / sqrtf(fmaxf(s, 1.0f));
    }
    __syncthreads();
    for (int i = t; i < 4096; i += 512) {
      int p = i >> 6, q = i & 63;
      float fullv = d2[p] * d2[q] * (ap[i] + (p == q ? 1.0f : 0.0f));
      unsigned short hi = f2bf(fullv);
      float lo = fullv - bf2f(hi);
      ((unsigned short*)(ws + OFF_A2H))[b * 4096 + i] = hi;
      ((unsigned short*)(ws + OFF_A2L))[b * 4096 + i] = f2bf(lo);
    }
    return;
  }
  const uint4* XH = (const uint4*)((const unsigned short*)(ws + OFF_XTH) +
                                   (size_t)(b * 4 + g) * 16384);
  const uint4* XL = (const uint4*)((const unsigned short*)(ws + OFF_XTL) +
                                   (size_t)(b * 4 + g) * 16384);
#pragma unroll
  for (int i = 0; i < 4; ++i) {
    int e = i * 512 + t;
    int f = e >> 4, s = e & 15;
    int slot = s ^ (f & 7);
    *(uint4*)(smH + f * 256 + slot * 16) = XH[e];
    *(uint4*)(smL + f * 256 + slot * 16) = XL[e];
  }
  int w = t >> 6, l = t & 63, ll = l & 15, lhi = l >> 4;
  int wm = w & 3, wn = w >> 2;
  const unsigned short* c1h = (const unsigned short*)(ws + OFF_C1H) +
                              ((size_t)g * 576 + rt * 64 + wm * 16 + ll) * 128;
  const unsigned short* c1l = (const unsigned short*)(ws + OFF_C1L) +
                              ((size_t)g * 576 + rt * 64 + wm * 16 + ll) * 128;
  bf16x8 Ah[4], Al[4];
#pragma unroll
  for (int ks = 0; ks < 4; ++ks) {
    Ah[ks] = *(const bf16x8*)(c1h + ks * 32 + lhi * 8);
    Al[ks] = *(const bf16x8*)(c1l + ks * 32 + lhi * 8);
  }
  __syncthreads();
  float* zb = ws + OFF_Z + ((size_t)b * 576 + rt * 64 + wm * 16) * 512 + g * 128 + wn * 64;
#pragma unroll
  for (int Nt = 0; Nt < 4; ++Nt) {
    int f = wn * 64 + Nt * 16 + ll;
    bf16x8 Bh[4], Bl[4];
#pragma unroll
    for (int ks = 0; ks < 4; ++ks) {
      int slot = (ks * 4 + lhi) ^ (f & 7);
      Bh[ks] = *(const bf16x8*)(smH + f * 256 + slot * 16);
      Bl[ks] = *(const bf16x8*)(smL + f * 256 + slot * 16);
    }
    f32x4 acc = {0.f, 0.f, 0.f, 0.f};
#pragma unroll
    for (int ks = 0; ks < 4; ++ks) {
      acc = __builtin_amdgcn_mfma_f32_16x16x32_bf16(Ah[ks], Bh[ks], acc, 0, 0, 0);
      acc = __builtin_amdgcn_mfma_f32_16x16x32_bf16(Ah[ks], Bl[ks], acc, 0, 0, 0);
      acc = __builtin_amdgcn_mfma_f32_16x16x32_bf16(Al[ks], Bh[ks], acc, 0, 0, 0);
    }
#pragma unroll
    for (int i = 0; i < 4; ++i)
      zb[(lhi * 4 + i) * 512 + Nt * 16 + ll] = acc[i];
  }
}

// -------- fused: x2[c,f] = relu(sum_k W1*z + b1*Tsum + tb1) ; v = W2*x2 via MFMA
__global__ __launch_bounds__(256) void k45m(const float* __restrict__ W1,
    const float* __restrict__ b1, const float* __restrict__ tb1,
    const float* __restrict__ W2, float* __restrict__ ws) {
  __shared__ float W1s[128];
  __shared__ float b1s[32];
  __shared__ float T1s[9];
  __shared__ __align__(16) unsigned short X2s[256 * 40];
  int b = blockIdx.x, p = blockIdx.y, t = threadIdx.x;
  if (t < 128) W1s[t] = W1[t];
  else if (t < 160) b1s[t - 128] = b1[t - 128];
  else if (t < 169) T1s[t - 160] = ws[OFF_T1 + p * 9 + (t - 160)];
  float tb = tb1[p];
  __syncthreads();
  const float* z = ws + OFF_Z + (size_t)b * 294912 + (size_t)p * 4608;
  unsigned short* vb = (unsigned short*)(ws + OFF_A);
  int w = t >> 6, l = t & 63, ll = l & 15, lhi = l >> 4;
  for (int pass = 0; pass < 2; ++pass) {
    int f = pass * 256 + t;
    float zv[9]; int gk[9];
    float tsum = 0.f;
#pragma unroll
    for (int k = 0; k < 9; ++k) {
      int fp = f + k - 4;
      bool val = (fp >= 0 && fp < 512);
      zv[k] = val ? z[k * 512 + fp] : 0.0f;
      gk[k] = val ? (fp >> 7) : 0;
      tsum += val ? T1s[k] : 0.0f;
    }
    float acc[32];
#pragma unroll
    for (int c = 0; c < 32; ++c) acc[c] = b1s[c] * tsum + tb;
#pragma unroll
    for (int k = 0; k < 9; ++k) {
      const float4* Wc = (const float4*)&W1s[gk[k] * 32];
      float zk = zv[k];
#pragma unroll
      for (int c4 = 0; c4 < 8; ++c4) {
        float4 wv = Wc[c4];
        acc[c4 * 4 + 0] += wv.x * zk;
        acc[c4 * 4 + 1] += wv.y * zk;
        acc[c4 * 4 + 2] += wv.z * zk;
        acc[c4 * 4 + 3] += wv.w * zk;
      }
    }
    __syncthreads();
#pragma unroll
    for (int grp = 0; grp < 4; ++grp) {
      unsigned short hs[8];
#pragma unroll
      for (int j = 0; j < 8; ++j) hs[j] = f2bf(fmaxf(acc[grp * 8 + j], 0.0f));
      *(uint4*)&X2s[t * 40 + grp * 8] = *(uint4*)hs;
    }
    __syncthreads();
    int g = pass * 2 + (w >> 1);
    const float* W2g = W2 + g * 1024;
    bf16x8 Ah[2], Al[2];
#pragma unroll
    for (int Mt = 0; Mt < 2; ++Mt) {
      const float* wp = W2g + (Mt * 16 + ll) * 32 + lhi * 8;
      float wv[8];
      *(float4*)&wv[0] = *(const float4*)wp;
      *(float4*)&wv[4] = *(const float4*)(wp + 4);
      unsigned short hh[8], lw[8];
#pragma unroll
      for (int j = 0; j < 8; ++j) {
        unsigned short h = f2bf(wv[j]);
        hh[j] = h;
        lw[j] = f2bf(wv[j] - bf2f(h));
      }
      Ah[Mt] = *(bf16x8*)hh;
      Al[Mt] = *(bf16x8*)lw;
    }
#pragma unroll
    for (int Nt = 0; Nt < 4; ++Nt) {
      int frow = w * 64 + Nt * 16 + ll;
      bf16x8 Bf = *(const bf16x8*)&X2s[frow * 40 + lhi * 8];
      f32x4 accv[2] = {{0.f, 0.f, 0.f, 0.f}, {0.f, 0.f, 0.f, 0.f}};
#pragma unroll
      for (int Mt = 0; Mt < 2; ++Mt) {
        accv[Mt] = __builtin_amdgcn_mfma_f32_16x16x32_bf16(Ah[Mt], Bf, accv[Mt], 0, 0, 0);
        accv[Mt] = __builtin_amdgcn_mfma_f32_16x16x32_bf16(Al[Mt], Bf, accv[Mt], 0, 0, 0);
      }
      int fglob = pass * 256 + frow;
#pragma unroll
      for (int Mt = 0; Mt < 2; ++Mt)
#pragma unroll
        for (int i = 0; i < 4; ++i) {
          int o = Mt * 16 + lhi * 4 + i;
          vb[((size_t)(b * 32 + o) * 64 + p) * 512 + fglob] = f2bf(accv[Mt][i]);
        }
    }
    __syncthreads();
  }
}

// ---- h2T[b,o,f,n] (bf16) = sum_m anorm2[g(f),n,m]*v[b,o,m,f] + b2[o] via MFMA ----
__global__ __launch_bounds__(256) void k5b_h2(const float* __restrict__ b2,
                                              float* __restrict__ ws) {
  __shared__ __align__(16) unsigned short vT[128 * 64];   // rows fl (128B), swizzled
  int b = blockIdx.x, o = blockIdx.y, g = blockIdx.z, t = threadIdx.x;
  const unsigned short* vbp = (const unsigned short*)(ws + OFF_A) +
                              (size_t)(b * 32 + o) * 32768;
  const uint4* vb4 = (const uint4*)vbp;
  unsigned char* vTw = (unsigned char*)vT;
  for (int i = t; i < 1024; i += 256) {
    int p = i >> 4, u = i & 15;
    uint4 val = vb4[p * 64 + g * 16 + u];
    const unsigned short* hv = (const unsigned short*)&val;
#pragma unroll
    for (int e = 0; e < 8; ++e) {
      int fl = u * 8 + e;
      int addr = fl * 128 + ((p * 2) ^ ((((fl & 7) ^ (fl >> 3)) & 7) << 4));
      *(unsigned short*)(vTw + addr) = hv[e];
    }
  }
  int w = t >> 6, l = t & 63, ll = l & 15, lhi = l >> 4;
  const unsigned short* a2h = (const unsigned short*)(ws + OFF_A2H) + g * 4096;
  const unsigned short* a2l = (const unsigned short*)(ws + OFF_A2L) + g * 4096;
  bf16x8 Ah[4][2], Al[4][2];
#pragma unroll
  for (int Mt = 0; Mt < 4; ++Mt)
#pragma unroll
    for (int ks = 0; ks < 2; ++ks) {
      int idx = (Mt * 16 + ll) * 64 + ks * 32 + lhi * 8;
      Ah[Mt][ks] = *(const bf16x8*)(a2h + idx);
      Al[Mt][ks] = *(const bf16x8*)(a2l + idx);
    }
  float bias = b2[o];
  __syncthreads();
  unsigned short* h2T = (unsigned short*)(ws + OFF_B) + (size_t)(b * 32 + o) * 32768;
  const unsigned char* vTr = (const unsigned char*)vT;
#pragma unroll
  for (int fi = 0; fi < 2; ++fi) {
    int fgl = w * 2 + fi;
    int fl = fgl * 16 + ll;
    int swz = (((fl & 7) ^ (fl >> 3)) & 7) << 4;
    bf16x8 Bf[2];
#pragma unroll
    for (int ks = 0; ks < 2; ++ks)
      Bf[ks] = *(const bf16x8*)(vTr + fl * 128 + ((ks * 64 + lhi * 16) ^ swz));
#pragma unroll
    for (int Mt = 0; Mt < 4; ++Mt) {
      f32x4 acc = {0.f, 0.f, 0.f, 0.f};
      acc = __builtin_amdgcn_mfma_f32_16x16x32_bf16(Ah[Mt][0], Bf[0], acc, 0, 0, 0);
      acc = __builtin_amdgcn_mfma_f32_16x16x32_bf16(Al[Mt][0], Bf[0], acc, 0, 0, 0);
      acc = __builtin_amdgcn_mfma_f32_16x16x32_bf16(Ah[Mt][1], Bf[1], acc, 0, 0, 0);
      acc = __builtin_amdgcn_mfma_f32_16x16x32_bf16(Al[Mt][1], Bf[1], acc, 0, 0, 0);
      int f = g * 128 + fgl * 16 + ll;
      int n0 = Mt * 16 + lhi * 4;
      unsigned short hs[4];
#pragma unroll
      for (int i2 = 0; i2 < 4; ++i2) hs[i2] = f2bf(acc[i2] + bias);
      *(short4v*)(h2T + f * 64 + n0) = *(short4v*)hs;
    }
  }
}

// ------- conv2 via bf16 MFMA + tb2 + relu + mean partial + last-block final linear -------
#define L_TWB 66304    // 32 q * 912B
#define L_RED 95488    // 8 floats
#define L_FLAG 95520   // 1 uint
__global__ __launch_bounds__(512) void k6_conv2(const float* __restrict__ tb2,
    const float* __restrict__ Wout, const float* __restrict__ bout,
    float* __restrict__ ws, float* __restrict__ out) {
  __shared__ __align__(16) unsigned char sm[95524];
  int b = blockIdx.x, c = blockIdx.y, t = threadIdx.x;
  const uint4* h2T4 = (const uint4*)((const unsigned short*)(ws + OFF_B) +
                                     (size_t)(b * 32 + c) * 32768);
  for (int ci = t; ci < 4144; ci += 512) {
    int r = ci >> 3, slot = ci & 7;
    int f = r - 3;
    uint4 val = make_uint4(0u, 0u, 0u, 0u);
    if (f >= 0 && f < 512) val = h2T4[f * 8 + slot];
    *(uint4*)(sm + r * 128 + ((slot ^ (r & 7)) << 4)) = val;
  }
  const uint4* twg = (const uint4*)(ws + OFF_TWB);
  for (int ci = t; ci < 1792; ci += 512) {
    int q = ci / 56, rem = ci - q * 56;
    *(uint4*)(sm + L_TWB + q * 912 + rem * 16) = twg[ci];
  }
  __syncthreads();
  int w = t >> 6, l = t & 63;
  int ll = l & 15, lhi = l >> 4;
  bf16x8 A[2][14];
#pragma unroll
  for (int Mt = 0; Mt < 2; ++Mt)
#pragma unroll
    for (int ks = 0; ks < 14; ++ks) {
      int q = Mt * 16 + ll;
      A[Mt][ks] = *(const bf16x8*)(sm + L_TWB + q * 912 + (ks >> 1) * 128 +
                                   (ks & 1) * 64 + lhi * 16);
    }
  f32x4 zero = {0.f, 0.f, 0.f, 0.f};
  f32x4 acc[2][4];
#pragma unroll
  for (int Mt = 0; Mt < 2; ++Mt)
#pragma unroll
    for (int Nt = 0; Nt < 4; ++Nt) acc[Mt][Nt] = zero;
  int rbase = w * 64 + ll;
#pragma unroll
  for (int ks = 0; ks < 14; ++ks) {
    int rb = rbase + (ks >> 1);
    int x = (((ks & 1) * 4 + lhi) ^ (rb & 7)) << 4;
#pragma unroll
    for (int Nt = 0; Nt < 4; ++Nt) {
      bf16x8 Bf = *(const bf16x8*)(sm + (rb + Nt * 16) * 128 + x);
      acc[0][Nt] = __builtin_amdgcn_mfma_f32_16x16x32_bf16(A[0][ks], Bf, acc[0][Nt], 0, 0, 0);
      acc[1][Nt] = __builtin_amdgcn_mfma_f32_16x16x32_bf16(A[1][ks], Bf, acc[1][Nt], 0, 0, 0);
    }
  }
  float tbv[8];
#pragma unroll
  for (int Mt = 0; Mt < 2; ++Mt)
#pragma unroll
    for (int i = 0; i < 4; ++i) tbv[Mt * 4 + i] = tb2[Mt * 16 + lhi * 4 + i];
  float s = 0.f;
#pragma unroll
  for (int Mt = 0; Mt < 2; ++Mt)
#pragma unroll
    for (int Nt = 0; Nt < 4; ++Nt)
#pragma unroll
      for (int i = 0; i < 4; ++i)
        s += fmaxf(acc[Mt][Nt][i] + tbv[Mt * 4 + i], 0.0f);
#pragma unroll
  for (int off = 32; off > 0; off >>= 1) s += __shfl_down(s, off, 64);
  float* red = (float*)(sm + L_RED);
  if (l == 0) red[w] = s;
  __syncthreads();
  if (t == 0) {
    float tot = 0.f;
    for (int i = 0; i < 8; ++i) tot += red[i];
    atomicExch(&ws[OFF_PART + b * 32 + c], tot);   // device-scope visible store
    __threadfence();
    unsigned old = atomicAdd((unsigned*)(ws + OFF_CTR), 1u);
    *(volatile unsigned*)(sm + L_FLAG) = (old == 511u) ? 1u : 0u;
  }
  __syncthreads();
  if (*(volatile unsigned*)(sm + L_FLAG)) {        // last block: final mean + linear
    __threadfence();
    float* feat = (float*)sm;                       // reuse h2s area
    if (t < 512) feat[t] = ws[OFF_PART + t] * (1.0f / 16384.0f);
    __syncthreads();
    if (t < 160) {
      int bb = t / 10, j = t - bb * 10;
      float accf = bout[j];
      for (int c2 = 0; c2 < 32; ++c2) accf += feat[bb * 32 + c2] * Wout[j * 32 + c2];
      out[t] = accf;
    }
  }
}

extern "C" void kernel_launch(void* const* d_in, const int* in_sizes, int n_in,
                              void* d_out, int out_size, void* d_ws, size_t ws_size,
                              hipStream_t stream) {
  const float* x    = (const float*)d_in[0];
  const float* adj  = (const float*)d_in[1];
  const float* W1   = (const float*)d_in[2];
  const float* b1   = (const float*)d_in[3];
  const float* tw1  = (const float*)d_in[4];
  const float* tb1  = (const float*)d_in[5];
  const float* rp1  = (const float*)d_in[6];
  const float* W2   = (const float*)d_in[7];
  const float* b2   = (const float*)d_in[8];
  const float* tw2  = (const float*)d_in[9];
  const float* tb2  = (const float*)d_in[10];
  // d_in[11] = rp2 : unused (second pooled adjacency is dead in the reference)
  const float* Wout = (const float*)d_in[12];
  const float* bout = (const float*)d_in[13];
  float* out = (float*)d_out;
  float* ws = (float*)d_ws;

  prep1_kernel<<<157, 256, 0, stream>>>(adj, tw1, rp1, tw2, x, ws);
  prep2_kernel<<<384, 256, 0, stream>>>(adj, ws);
  prep3_kernel<<<1216, 256, 0, stream>>>(tw1, ws);
  kz_mfma     <<<dim3(16, 10, 4), 512, 0, stream>>>(ws);
  k45m        <<<dim3(16, 64), 256, 0, stream>>>(W1, b1, tb1, W2, ws);
  k5b_h2      <<<dim3(16, 32, 4), 256, 0, stream>>>(b2, ws);
  k6_conv2    <<<dim3(16, 32), 512, 0, stream>>>(tb2, Wout, bout, ws, out);
}